// Round 20
// baseline (1141.117 us; speedup 1.0000x reference)
//
#include <hip/hip_runtime.h>
#include <hip/hip_bf16.h>

#define BB   256
#define TCAP 51
#define TT   50
#define VV   10000
#define WDIM 512
#define HH   512
#define ICC  2048
#define G3H  1536
#define FCP  8

typedef __attribute__((ext_vector_type(8))) short short8v;
typedef __attribute__((ext_vector_type(4))) float f32x4;

__device__ __forceinline__ unsigned short f2bf(float f) {
    unsigned u; __builtin_memcpy(&u, &f, 4);
    unsigned r = (u + 0x7FFFu + ((u >> 16) & 1u)) >> 16;   // RNE
    return (unsigned short)r;
}
__device__ __forceinline__ float bf2f(unsigned short b) {
    unsigned u = ((unsigned)b) << 16; float f; __builtin_memcpy(&f, &u, 4); return f;
}
__device__ __forceinline__ short8v cvt8(float4 a, float4 b) {
    union { unsigned short u[8]; short8v v; } o;
    o.u[0] = f2bf(a.x); o.u[1] = f2bf(a.y); o.u[2] = f2bf(a.z); o.u[3] = f2bf(a.w);
    o.u[4] = f2bf(b.x); o.u[5] = f2bf(b.y); o.u[6] = f2bf(b.z); o.u[7] = f2bf(b.w);
    return o.v;
}
__device__ __forceinline__ float sigm(float x) { return 1.f / (1.f + expf(-x)); }

// ---------------- sort (stable, descending) + tail outputs (f32) ----------------
__global__ void sort_kernel(const int* __restrict__ cap_lens, const int* __restrict__ captions,
                            int* __restrict__ order_ws, int* __restrict__ len_ws,
                            int* __restrict__ caps_ws, float* __restrict__ out,
                            size_t predN) {
    __shared__ int s_order[BB];
    int i = threadIdx.x;
    int li = cap_lens[i];
    int rank = 0;
    for (int j = 0; j < BB; ++j) {
        int lj = cap_lens[j];
        rank += (lj > li) || (lj == li && j < i);
    }
    s_order[rank] = i;
    __syncthreads();
    int src = s_order[i];
    order_ws[i] = src;
    int len = cap_lens[src] - 1;
    len_ws[i] = len;
    for (int t = 0; t < TCAP; ++t) {
        int c = captions[src * TCAP + t];
        caps_ws[i * TCAP + t] = c;
        out[predN + (size_t)i * TCAP + t] = (float)c;
    }
    out[predN + (size_t)BB * TCAP + i]      = (float)len;
    out[predN + (size_t)BB * TCAP + BB + i] = (float)src;
}

// ---------------- gather image rows (sorted) -> bf16 ----------------
__global__ void gather_imgb(const float* __restrict__ image_code, const int* __restrict__ order_ws,
                            unsigned short* __restrict__ imgb) {
    int i = blockIdx.x * 256 + threadIdx.x;       // 65536 total, 8 elems each
    int p = i >> 8, c8 = (i & 255) << 3;
    const float* s = image_code + (size_t)order_ws[p] * ICC + c8;
    float4 v0 = *(const float4*)s, v1 = *(const float4*)(s + 4);
    *(short8v*)&imgb[(size_t)p * ICC + c8] = cvt8(v0, v1);
}

// ---------------- strided f32 -> bf16 matrix convert ----------------
__global__ void cvt_mat(const float* __restrict__ src, int src_ld, int src_off,
                        unsigned short* __restrict__ dst, int dst_ld, int dst_off,
                        int cols, int n8) {
    int i = blockIdx.x * 256 + threadIdx.x;
    if (i < n8) {
        int cpr = cols >> 3;
        int row = i / cpr, c8 = (i - row * cpr) << 3;
        const float* s = src + (size_t)row * src_ld + src_off + c8;
        float4 v0 = *(const float4*)s, v1 = *(const float4*)(s + 4);
        *(short8v*)&dst[(size_t)row * dst_ld + dst_off + c8] = cvt8(v0, v1);
    }
}

// ---------------- front GEMM: [256 x 2560] = imgb @ wcomb^T -> h0, h1 (bf16), gi_img ------
__global__ __launch_bounds__(256) void gemm_front(
    const unsigned short* __restrict__ imgb,    // [256][2048]
    const unsigned short* __restrict__ wcomb,   // [2560][2048]
    const float* __restrict__ init_b,           // [1024]
    const float* __restrict__ b_ih0,            // [1536]
    unsigned short* __restrict__ h0s0,          // [256][512] bf16
    unsigned short* __restrict__ h1s0,          // [256][512] bf16
    float* __restrict__ gi_img) {
    const int p0 = blockIdx.y * 64;
    const int c0 = blockIdx.x * 64;
    const int tid = threadIdx.x;
    __shared__ unsigned short As[64][64 + FCP], Bs[64][64 + FCP];
    const int lane = tid & 63, w = tid >> 6;
    f32x4 acc[4] = {};
    for (int k0 = 0; k0 < ICC; k0 += 64) {
#pragma unroll
        for (int v = 0; v < 2; ++v) {
            int e = tid + v * 256;
            int rr = e >> 3, kk = (e & 7) * 8;
            *(short8v*)&As[rr][kk] = *(const short8v*)&imgb[(size_t)(p0 + rr) * ICC + k0 + kk];
            *(short8v*)&Bs[rr][kk] = *(const short8v*)&wcomb[(size_t)(c0 + rr) * ICC + k0 + kk];
        }
        __syncthreads();
#pragma unroll
        for (int ks = 0; ks < 64; ks += 32) {
            short8v a = *(const short8v*)&As[w * 16 + (lane & 15)][ks + (lane >> 4) * 8];
#pragma unroll
            for (int n = 0; n < 4; ++n) {
                short8v b = *(const short8v*)&Bs[n * 16 + (lane & 15)][ks + (lane >> 4) * 8];
                acc[n] = __builtin_amdgcn_mfma_f32_16x16x32_bf16(a, b, acc[n], 0, 0, 0);
            }
        }
        __syncthreads();
    }
#pragma unroll
    for (int n = 0; n < 4; ++n) {
        int cc = c0 + n * 16 + (lane & 15);
#pragma unroll
        for (int r = 0; r < 4; ++r) {
            int pr = p0 + w * 16 + (lane >> 4) * 4 + r;
            float v = acc[n][r];
            if (cc < 1024) {
                v += init_b[cc];
                unsigned short b = f2bf(v);
                if (cc < 512) h0s0[(size_t)pr * 512 + cc] = b;
                else          h1s0[(size_t)pr * 512 + (cc - 512)] = b;
            } else {
                gi_img[(size_t)pr * G3H + (cc - 1024)] = v + b_ih0[cc - 1024];
            }
        }
    }
}

// ---------------- gi GEMM: gi_all[t,p,:] = emb_bf16 @ w_ihe^T + gi_img ----------------
__global__ __launch_bounds__(256) void gemm_giemb(
    const unsigned short* __restrict__ embb,    // [VV][512]
    const unsigned short* __restrict__ wihe,    // [1536][512]
    const float* __restrict__ gi_img,           // [256][1536]
    const int* __restrict__ caps_ws, const int* __restrict__ len_ws,
    float* __restrict__ gi_all) {
    const int r0 = blockIdx.y * 64;
    const int t = r0 >> 8, p0 = r0 & 255;
    if (len_ws[p0] <= t) return;
    const int c0 = blockIdx.x * 64;
    const int tid = threadIdx.x;
    __shared__ unsigned short As[64][64 + FCP], Bs[64][64 + FCP];
    __shared__ int s_arow[64];
    if (tid < 64) s_arow[tid] = caps_ws[(p0 + tid) * TCAP + t];
    __syncthreads();
    const int lane = tid & 63, w = tid >> 6;
    f32x4 acc[4] = {};
    for (int k0 = 0; k0 < WDIM; k0 += 64) {
#pragma unroll
        for (int v = 0; v < 2; ++v) {
            int e = tid + v * 256;
            int rr = e >> 3, kk = (e & 7) * 8;
            *(short8v*)&As[rr][kk] = *(const short8v*)&embb[(size_t)s_arow[rr] * WDIM + k0 + kk];
            *(short8v*)&Bs[rr][kk] = *(const short8v*)&wihe[(size_t)(c0 + rr) * WDIM + k0 + kk];
        }
        __syncthreads();
#pragma unroll
        for (int ks = 0; ks < 64; ks += 32) {
            short8v a = *(const short8v*)&As[w * 16 + (lane & 15)][ks + (lane >> 4) * 8];
#pragma unroll
            for (int n = 0; n < 4; ++n) {
                short8v b = *(const short8v*)&Bs[n * 16 + (lane & 15)][ks + (lane >> 4) * 8];
                acc[n] = __builtin_amdgcn_mfma_f32_16x16x32_bf16(a, b, acc[n], 0, 0, 0);
            }
        }
        __syncthreads();
    }
#pragma unroll
    for (int n = 0; n < 4; ++n) {
        int cc = c0 + n * 16 + (lane & 15);
#pragma unroll
        for (int r = 0; r < 4; ++r) {
            int pr = p0 + w * 16 + (lane >> 4) * 4 + r;
            if (t < len_ws[pr])
                gi_all[((size_t)t * BB + pr) * G3H + cc] = acc[n][r] + gi_img[(size_t)pr * G3H + cc];
        }
    }
}

// ---------------- fused stage: blocks 0-95 gru (3-role v3), blocks 96-409 fc v2 @ t=s-3 -----
// gru: identical to validated round-18/19. fc: 128-row pair; A1/A2/B depth-2 register
// prefetch + double-buffered LDS (same pattern as gru v3), ONE barrier per k-iteration.
__global__ __launch_bounds__(256, 1) void gru_fc_stage(int s,
    const unsigned short* __restrict__ h0_rd, unsigned short* __restrict__ h0_wr,
    float* __restrict__ gx_wr, const float* __restrict__ gx_rd,
    const unsigned short* __restrict__ h1_rd, unsigned short* __restrict__ h1_wr,
    unsigned short* __restrict__ h1x,
    const unsigned short* __restrict__ whh0b,   // [1536][512]
    const unsigned short* __restrict__ wih1b,   // [1536][512]
    const unsigned short* __restrict__ whh1b,   // [1536][512]
    const float* __restrict__ b_hh0, const float* __restrict__ gi_all,
    const float* __restrict__ b_ih1, const float* __restrict__ b_hh1,
    const unsigned short* __restrict__ fcwb,    // [VV][512]
    const float* __restrict__ fc_b,
    float* __restrict__ out,
    const int* __restrict__ len_ws) {
    __shared__ __align__(16) unsigned char smem_raw[55296];   // 54 KB, unioned
    const int bid = blockIdx.x;
    const int tid = threadIdx.x, lane = tid & 63, w = tid >> 6;

    if (bid < 96) {
        // ================= GRU part (validated) =================
        const int role = bid >> 5;
        const int sub = bid & 31;
        const int cc0 = (sub & 7) * 64;
        const int p0 = (sub >> 3) * 64;
        const int t = s - role;
        if (t < 0 || t >= TT) return;
        if (len_ws[p0] <= t) return;
        unsigned short (*Bs)[3][64][72] =
            reinterpret_cast<unsigned short (*)[3][64][72]>(smem_raw);
        const unsigned short* Arows = (role == 2) ? h1_rd : h0_rd;
        const unsigned short* Bw = (role == 0) ? whh0b : (role == 1) ? wih1b : whh1b;
        const int rr0 = tid >> 3, kk0 = (tid & 7) * 8;

        const int arow = p0 + w * 16 + (lane & 15);
        const int akoff = (lane >> 4) * 8;
        short8v af[16];
#pragma unroll
        for (int kc = 0; kc < 8; ++kc) {
            af[kc * 2]     = *(const short8v*)&Arows[(size_t)arow * 512 + kc * 64 + akoff];
            af[kc * 2 + 1] = *(const short8v*)&Arows[(size_t)arow * 512 + kc * 64 + 32 + akoff];
        }

        f32x4 aG0[4] = {}, aG1[4] = {}, aG2[4] = {};
        short8v pb[2][6];

#define LOADB(SL, KC) {                                                              \
    size_t ko = (size_t)(KC) * 64 + kk0;                                             \
    pb[SL][0] = *(const short8v*)&Bw[(size_t)(cc0 + rr0) * 512 + ko];                \
    pb[SL][1] = *(const short8v*)&Bw[(size_t)(cc0 + rr0 + 32) * 512 + ko];           \
    pb[SL][2] = *(const short8v*)&Bw[(size_t)(512 + cc0 + rr0) * 512 + ko];          \
    pb[SL][3] = *(const short8v*)&Bw[(size_t)(512 + cc0 + rr0 + 32) * 512 + ko];     \
    pb[SL][4] = *(const short8v*)&Bw[(size_t)(1024 + cc0 + rr0) * 512 + ko];         \
    pb[SL][5] = *(const short8v*)&Bw[(size_t)(1024 + cc0 + rr0 + 32) * 512 + ko]; }

        LOADB(0, 0);
        LOADB(1, 1);
#pragma unroll
        for (int kc = 0; kc < 8; ++kc) {
            const int sl = kc & 1;
            *(short8v*)&Bs[sl][0][rr0][kk0]      = pb[sl][0];
            *(short8v*)&Bs[sl][0][rr0 + 32][kk0] = pb[sl][1];
            *(short8v*)&Bs[sl][1][rr0][kk0]      = pb[sl][2];
            *(short8v*)&Bs[sl][1][rr0 + 32][kk0] = pb[sl][3];
            *(short8v*)&Bs[sl][2][rr0][kk0]      = pb[sl][4];
            *(short8v*)&Bs[sl][2][rr0 + 32][kk0] = pb[sl][5];
            __syncthreads();
            if (kc < 6) LOADB(sl, kc + 2);
#pragma unroll
            for (int ks = 0; ks < 2; ++ks) {
                short8v a = af[kc * 2 + ks];
#pragma unroll
                for (int n = 0; n < 4; ++n) {
                    int br = n * 16 + (lane & 15), bk = ks * 32 + (lane >> 4) * 8;
                    short8v b0 = *(const short8v*)&Bs[sl][0][br][bk];
                    aG0[n] = __builtin_amdgcn_mfma_f32_16x16x32_bf16(a, b0, aG0[n], 0, 0, 0);
                    short8v b1 = *(const short8v*)&Bs[sl][1][br][bk];
                    aG1[n] = __builtin_amdgcn_mfma_f32_16x16x32_bf16(a, b1, aG1[n], 0, 0, 0);
                    short8v b2 = *(const short8v*)&Bs[sl][2][br][bk];
                    aG2[n] = __builtin_amdgcn_mfma_f32_16x16x32_bf16(a, b2, aG2[n], 0, 0, 0);
                }
            }
        }
#undef LOADB

        if (role == 0) {
#pragma unroll
            for (int n = 0; n < 4; ++n) {
                int cc = cc0 + n * 16 + (lane & 15);
                float bR = b_hh0[cc], bZ = b_hh0[512 + cc], bN = b_hh0[1024 + cc];
#pragma unroll
                for (int r = 0; r < 4; ++r) {
                    int p = p0 + w * 16 + (lane >> 4) * 4 + r;
                    const float* gi = gi_all + ((size_t)t * BB + p) * G3H;
                    float rr_ = sigm(gi[cc] + aG0[n][r] + bR);
                    float zz  = sigm(gi[512 + cc] + aG1[n][r] + bZ);
                    float nn  = tanhf(gi[1024 + cc] + rr_ * (aG2[n][r] + bN));
                    float hold = bf2f(h0_rd[(size_t)p * 512 + cc]);
                    float hnew = (t < len_ws[p]) ? (1.f - zz) * nn + zz * hold : hold;
                    h0_wr[(size_t)p * 512 + cc] = f2bf(hnew);
                }
            }
        } else if (role == 1) {
#pragma unroll
            for (int n = 0; n < 4; ++n) {
                int cc = cc0 + n * 16 + (lane & 15);
                float bR = b_ih1[cc], bZ = b_ih1[512 + cc], bN = b_ih1[1024 + cc];
#pragma unroll
                for (int r = 0; r < 4; ++r) {
                    int p = p0 + w * 16 + (lane >> 4) * 4 + r;
                    float* gx = gx_wr + (size_t)p * G3H;
                    gx[cc]        = aG0[n][r] + bR;
                    gx[512 + cc]  = aG1[n][r] + bZ;
                    gx[1024 + cc] = aG2[n][r] + bN;
                }
            }
        } else {
#pragma unroll
            for (int n = 0; n < 4; ++n) {
                int cc = cc0 + n * 16 + (lane & 15);
                float bR = b_hh1[cc], bZ = b_hh1[512 + cc], bN = b_hh1[1024 + cc];
#pragma unroll
                for (int r = 0; r < 4; ++r) {
                    int p = p0 + w * 16 + (lane >> 4) * 4 + r;
                    const float* gx = gx_rd + (size_t)p * G3H;
                    float rr_ = sigm(gx[cc] + aG0[n][r] + bR);
                    float zz  = sigm(gx[512 + cc] + aG1[n][r] + bZ);
                    float nn  = tanhf(gx[1024 + cc] + rr_ * (aG2[n][r] + bN));
                    float hold = bf2f(h1_rd[(size_t)p * 512 + cc]);
                    float hnew = (t < len_ws[p]) ? (1.f - zz) * nn + zz * hold : hold;
                    unsigned short hb = f2bf(hnew);
                    h1_wr[(size_t)p * 512 + cc] = hb;
                    h1x[((size_t)t * BB + p) * 512 + cc] = hb;
                }
            }
        }
        return;
    }

    // ======= FC part: t = s-3; 128-row pair; depth-2 prefetch + LDS dbuf, 1 barrier/iter =======
    const int t = s - 3;
    if (t < 0 || t >= TT) return;
    const int idx = bid - 96;                    // 0..313
    const int c0 = (idx % 157) * 64;
    const int p0 = (idx / 157) * 128;            // 0 or 128
    if (len_ws[p0] <= t) {                       // all 128 rows masked (sorted desc) -> zeros
        for (int e = tid; e < 128 * 16; e += 256) {
            int rl = e >> 4, c = c0 + (e & 15) * 4;
            if (c < VV) {
                float4 z = {0.f, 0.f, 0.f, 0.f};
                *(float4*)&out[((size_t)(p0 + rl) * TT + t) * VV + c] = z;
            }
        }
        return;
    }
    // LDS: 2 buffers x 3 tiles (A1, A2, B) x 64x72 ushorts = 55296 B
    unsigned short* smu = reinterpret_cast<unsigned short*>(smem_raw);
    const int rr0 = tid >> 3, kk0 = (tid & 7) * 8;
    f32x4 acc1[4] = {}, acc2[4] = {};
    short8v pf[2][6];

#define LOADF(SL, KC) {                                                                   \
    size_t ko = (size_t)(KC) * 64 + kk0;                                                  \
    pf[SL][0] = *(const short8v*)&h1x[((size_t)(t * BB + p0 + rr0)) * 512 + ko];          \
    pf[SL][1] = *(const short8v*)&h1x[((size_t)(t * BB + p0 + rr0 + 32)) * 512 + ko];     \
    pf[SL][2] = *(const short8v*)&h1x[((size_t)(t * BB + p0 + 64 + rr0)) * 512 + ko];     \
    pf[SL][3] = *(const short8v*)&h1x[((size_t)(t * BB + p0 + 64 + rr0 + 32)) * 512 + ko];\
    int bc1 = c0 + rr0, bc2 = c0 + rr0 + 32;                                              \
    short8v bv1 = {}, bv2 = {};                                                           \
    if (bc1 < VV) bv1 = *(const short8v*)&fcwb[(size_t)bc1 * 512 + ko];                   \
    if (bc2 < VV) bv2 = *(const short8v*)&fcwb[(size_t)bc2 * 512 + ko];                   \
    pf[SL][4] = bv1; pf[SL][5] = bv2; }

    LOADF(0, 0);
    LOADF(1, 1);
#pragma unroll
    for (int kc = 0; kc < 8; ++kc) {
        const int sl = kc & 1;
        unsigned short* tA1 = smu + (sl * 3 + 0) * 4608;   // 64*72
        unsigned short* tA2 = smu + (sl * 3 + 1) * 4608;
        unsigned short* tB  = smu + (sl * 3 + 2) * 4608;
        *(short8v*)&tA1[rr0 * 72 + kk0]        = pf[sl][0];
        *(short8v*)&tA1[(rr0 + 32) * 72 + kk0] = pf[sl][1];
        *(short8v*)&tA2[rr0 * 72 + kk0]        = pf[sl][2];
        *(short8v*)&tA2[(rr0 + 32) * 72 + kk0] = pf[sl][3];
        *(short8v*)&tB[rr0 * 72 + kk0]         = pf[sl][4];
        *(short8v*)&tB[(rr0 + 32) * 72 + kk0]  = pf[sl][5];
        __syncthreads();
        if (kc < 6) LOADF(sl, kc + 2);
#pragma unroll
        for (int ks = 0; ks < 2; ++ks) {
            int ar = w * 16 + (lane & 15), ak = ks * 32 + (lane >> 4) * 8;
            short8v a1 = *(const short8v*)&tA1[ar * 72 + ak];
            short8v a2 = *(const short8v*)&tA2[ar * 72 + ak];
#pragma unroll
            for (int n = 0; n < 4; ++n) {
                short8v b = *(const short8v*)&tB[(n * 16 + (lane & 15)) * 72 + ak];
                acc1[n] = __builtin_amdgcn_mfma_f32_16x16x32_bf16(a1, b, acc1[n], 0, 0, 0);
                acc2[n] = __builtin_amdgcn_mfma_f32_16x16x32_bf16(a2, b, acc2[n], 0, 0, 0);
            }
        }
    }
#undef LOADF
#pragma unroll
    for (int n = 0; n < 4; ++n) {
        int c = c0 + n * 16 + (lane & 15);
        if (c < VV) {
            float bias = fc_b[c];
#pragma unroll
            for (int r = 0; r < 4; ++r) {
                int pr1 = p0 + w * 16 + (lane >> 4) * 4 + r;
                int pr2 = pr1 + 64;
                bool a1 = (t < len_ws[pr1]);
                bool a2 = (t < len_ws[pr2]);
                out[((size_t)pr1 * TT + t) * VV + c] = a1 ? (acc1[n][r] + bias) : 0.f;
                out[((size_t)pr2 * TT + t) * VV + c] = a2 ? (acc2[n][r] + bias) : 0.f;
            }
        }
    }
}

// ---------------- launch ----------------
extern "C" void kernel_launch(void* const* d_in, const int* in_sizes, int n_in,
                              void* d_out, int out_size, void* d_ws, size_t ws_size,
                              hipStream_t stream) {
    const float* image_code = (const float*)d_in[0];
    const int*   captions   = (const int*)d_in[1];
    const int*   cap_lens   = (const int*)d_in[2];
    const float* embed_w    = (const float*)d_in[3];
    const float* init_w     = (const float*)d_in[4];
    const float* init_b     = (const float*)d_in[5];
    const float* w_ih0      = (const float*)d_in[6];
    const float* w_hh0      = (const float*)d_in[7];
    const float* b_ih0      = (const float*)d_in[8];
    const float* b_hh0      = (const float*)d_in[9];
    const float* w_ih1      = (const float*)d_in[10];
    const float* w_hh1      = (const float*)d_in[11];
    const float* b_ih1      = (const float*)d_in[12];
    const float* b_hh1      = (const float*)d_in[13];
    const float* fc_w       = (const float*)d_in[14];
    const float* fc_b       = (const float*)d_in[15];
    float* out = (float*)d_out;

    const size_t tail = (size_t)BB * TCAP + 2 * BB;     // 13,568
    const size_t predN = (size_t)out_size - tail;       // BB*TT*VV

    // ---- workspace ----
    char* ws = (char*)d_ws;
    int*   order_ws = (int*)(ws + 0);
    int*   len_ws   = (int*)(ws + 1024);
    int*   caps_ws  = (int*)(ws + 2048);
    unsigned short* h0s[2] = {(unsigned short*)(ws + 54272),  (unsigned short*)(ws + 316416)};
    unsigned short* h1s[2] = {(unsigned short*)(ws + 578560), (unsigned short*)(ws + 840704)};
    float* gxb[2] = {(float*)(ws + 1102848), (float*)(ws + 2675712)};
    float* gi_img   = (float*)(ws + 4248576);
    float* gi_all   = (float*)(ws + 5821440);
    unsigned short* h1x  = (unsigned short*)(ws + 84464640);
    unsigned short* fcwb = (unsigned short*)(ws + 97571840);
    unsigned short* whh0b_s = (unsigned short*)(ws + 110000128);
    unsigned short* wih1b_s = (unsigned short*)(ws + 111572992);
    unsigned short* whh1b_s = (unsigned short*)(ws + 113145856);

    // ---- bf16 staging in d_out's predictions region (consumed before fc writes) ----
    char* ob = (char*)d_out;
    unsigned short* imgb   = (unsigned short*)(ob + 0);          //  1,048,576 B
    unsigned short* wihe   = (unsigned short*)(ob + 1048576);    //  1,572,864 B
    unsigned short* wcomb  = (unsigned short*)(ob + 4194304);    // 10,485,760 B
    unsigned short* embb   = (unsigned short*)(ob + 16777216);   // 10,240,000 B

    dim3 blk(256);
    hipLaunchKernelGGL(sort_kernel, dim3(1), blk, 0, stream,
                       cap_lens, captions, order_ws, len_ws, caps_ws, out, predN);
    hipLaunchKernelGGL(gather_imgb, dim3(256), blk, 0, stream, image_code, order_ws, imgb);
    hipLaunchKernelGGL(cvt_mat, dim3(1024), blk, 0, stream,
                       init_w, ICC, 0, wcomb, ICC, 0, ICC, 1024 * ICC / 8);
    hipLaunchKernelGGL(cvt_mat, dim3(1536), blk, 0, stream,
                       w_ih0, ICC + WDIM, 0, wcomb + (size_t)1024 * ICC, ICC, 0, ICC, G3H * ICC / 8);
    hipLaunchKernelGGL(cvt_mat, dim3(384), blk, 0, stream,
                       w_ih0, ICC + WDIM, ICC, wihe, WDIM, 0, WDIM, G3H * WDIM / 8);
    hipLaunchKernelGGL(cvt_mat, dim3(2500), blk, 0, stream,
                       embed_w, WDIM, 0, embb, WDIM, 0, WDIM, VV * WDIM / 8);
    hipLaunchKernelGGL(cvt_mat, dim3(2500), blk, 0, stream,
                       fc_w, WDIM, 0, fcwb, WDIM, 0, WDIM, VV * WDIM / 8);
    hipLaunchKernelGGL(cvt_mat, dim3(384), blk, 0, stream,
                       w_hh0, WDIM, 0, whh0b_s, WDIM, 0, WDIM, G3H * WDIM / 8);
    hipLaunchKernelGGL(cvt_mat, dim3(384), blk, 0, stream,
                       w_ih1, WDIM, 0, wih1b_s, WDIM, 0, WDIM, G3H * WDIM / 8);
    hipLaunchKernelGGL(cvt_mat, dim3(384), blk, 0, stream,
                       w_hh1, WDIM, 0, whh1b_s, WDIM, 0, WDIM, G3H * WDIM / 8);

    hipLaunchKernelGGL(gemm_front, dim3(40, 4), blk, 0, stream,
                       imgb, wcomb, init_b, b_ih0, h0s[0], h1s[0], gi_img);
    hipLaunchKernelGGL(gemm_giemb, dim3(24, 200), blk, 0, stream,
                       embb, wihe, gi_img, caps_ws, len_ws, gi_all);

    // 53 fused stages: stage s = { l0@s, gx1@s-1, l1h@s-2, fc@s-3 }
    for (int s = 0; s <= TT + 2; ++s) {
        int q = s & 1;
        hipLaunchKernelGGL(gru_fc_stage, dim3(96 + 314), blk, 0, stream, s,
                           h0s[q], h0s[q ^ 1],
                           gxb[q ^ 1], gxb[q],
                           h1s[q], h1s[q ^ 1],
                           h1x, whh0b_s, wih1b_s, whh1b_s,
                           b_hh0, gi_all, b_ih1, b_hh1,
                           fcwb, fc_b, out, len_ws);
    }
}

// Round 21
// 1093.430 us; speedup vs baseline: 1.0436x; 1.0436x over previous
//
#include <hip/hip_runtime.h>
#include <hip/hip_bf16.h>

#define BB   256
#define TCAP 51
#define TT   50
#define VV   10000
#define WDIM 512
#define HH   512
#define ICC  2048
#define G3H  1536
#define FCP  8

typedef __attribute__((ext_vector_type(8))) short short8v;
typedef __attribute__((ext_vector_type(4))) float f32x4;

__device__ __forceinline__ unsigned short f2bf(float f) {
    unsigned u; __builtin_memcpy(&u, &f, 4);
    unsigned r = (u + 0x7FFFu + ((u >> 16) & 1u)) >> 16;   // RNE
    return (unsigned short)r;
}
__device__ __forceinline__ float bf2f(unsigned short b) {
    unsigned u = ((unsigned)b) << 16; float f; __builtin_memcpy(&f, &u, 4); return f;
}
__device__ __forceinline__ short8v cvt8(float4 a, float4 b) {
    union { unsigned short u[8]; short8v v; } o;
    o.u[0] = f2bf(a.x); o.u[1] = f2bf(a.y); o.u[2] = f2bf(a.z); o.u[3] = f2bf(a.w);
    o.u[4] = f2bf(b.x); o.u[5] = f2bf(b.y); o.u[6] = f2bf(b.z); o.u[7] = f2bf(b.w);
    return o.v;
}
__device__ __forceinline__ float sigm(float x) { return 1.f / (1.f + expf(-x)); }

// ---------------- sort (stable, descending) + tail outputs (f32) ----------------
__global__ void sort_kernel(const int* __restrict__ cap_lens, const int* __restrict__ captions,
                            int* __restrict__ order_ws, int* __restrict__ len_ws,
                            int* __restrict__ caps_ws, float* __restrict__ out,
                            size_t predN) {
    __shared__ int s_order[BB];
    int i = threadIdx.x;
    int li = cap_lens[i];
    int rank = 0;
    for (int j = 0; j < BB; ++j) {
        int lj = cap_lens[j];
        rank += (lj > li) || (lj == li && j < i);
    }
    s_order[rank] = i;
    __syncthreads();
    int src = s_order[i];
    order_ws[i] = src;
    int len = cap_lens[src] - 1;
    len_ws[i] = len;
    for (int t = 0; t < TCAP; ++t) {
        int c = captions[src * TCAP + t];
        caps_ws[i * TCAP + t] = c;
        out[predN + (size_t)i * TCAP + t] = (float)c;
    }
    out[predN + (size_t)BB * TCAP + i]      = (float)len;
    out[predN + (size_t)BB * TCAP + BB + i] = (float)src;
}

// ---------------- gather image rows (sorted) -> bf16 ----------------
__global__ void gather_imgb(const float* __restrict__ image_code, const int* __restrict__ order_ws,
                            unsigned short* __restrict__ imgb) {
    int i = blockIdx.x * 256 + threadIdx.x;       // 65536 total, 8 elems each
    int p = i >> 8, c8 = (i & 255) << 3;
    const float* s = image_code + (size_t)order_ws[p] * ICC + c8;
    float4 v0 = *(const float4*)s, v1 = *(const float4*)(s + 4);
    *(short8v*)&imgb[(size_t)p * ICC + c8] = cvt8(v0, v1);
}

// ---------------- strided f32 -> bf16 matrix convert ----------------
__global__ void cvt_mat(const float* __restrict__ src, int src_ld, int src_off,
                        unsigned short* __restrict__ dst, int dst_ld, int dst_off,
                        int cols, int n8) {
    int i = blockIdx.x * 256 + threadIdx.x;
    if (i < n8) {
        int cpr = cols >> 3;
        int row = i / cpr, c8 = (i - row * cpr) << 3;
        const float* s = src + (size_t)row * src_ld + src_off + c8;
        float4 v0 = *(const float4*)s, v1 = *(const float4*)(s + 4);
        *(short8v*)&dst[(size_t)row * dst_ld + dst_off + c8] = cvt8(v0, v1);
    }
}

// ---------------- front GEMM: [256 x 2560] = imgb @ wcomb^T -> h0, h1 (bf16), gi_img ------
__global__ __launch_bounds__(256) void gemm_front(
    const unsigned short* __restrict__ imgb,    // [256][2048]
    const unsigned short* __restrict__ wcomb,   // [2560][2048]
    const float* __restrict__ init_b,           // [1024]
    const float* __restrict__ b_ih0,            // [1536]
    unsigned short* __restrict__ h0s0,          // [256][512] bf16
    unsigned short* __restrict__ h1s0,          // [256][512] bf16
    float* __restrict__ gi_img) {
    const int p0 = blockIdx.y * 64;
    const int c0 = blockIdx.x * 64;
    const int tid = threadIdx.x;
    __shared__ unsigned short As[64][64 + FCP], Bs[64][64 + FCP];
    const int lane = tid & 63, w = tid >> 6;
    f32x4 acc[4] = {};
    for (int k0 = 0; k0 < ICC; k0 += 64) {
#pragma unroll
        for (int v = 0; v < 2; ++v) {
            int e = tid + v * 256;
            int rr = e >> 3, kk = (e & 7) * 8;
            *(short8v*)&As[rr][kk] = *(const short8v*)&imgb[(size_t)(p0 + rr) * ICC + k0 + kk];
            *(short8v*)&Bs[rr][kk] = *(const short8v*)&wcomb[(size_t)(c0 + rr) * ICC + k0 + kk];
        }
        __syncthreads();
#pragma unroll
        for (int ks = 0; ks < 64; ks += 32) {
            short8v a = *(const short8v*)&As[w * 16 + (lane & 15)][ks + (lane >> 4) * 8];
#pragma unroll
            for (int n = 0; n < 4; ++n) {
                short8v b = *(const short8v*)&Bs[n * 16 + (lane & 15)][ks + (lane >> 4) * 8];
                acc[n] = __builtin_amdgcn_mfma_f32_16x16x32_bf16(a, b, acc[n], 0, 0, 0);
            }
        }
        __syncthreads();
    }
#pragma unroll
    for (int n = 0; n < 4; ++n) {
        int cc = c0 + n * 16 + (lane & 15);
#pragma unroll
        for (int r = 0; r < 4; ++r) {
            int pr = p0 + w * 16 + (lane >> 4) * 4 + r;
            float v = acc[n][r];
            if (cc < 1024) {
                v += init_b[cc];
                unsigned short b = f2bf(v);
                if (cc < 512) h0s0[(size_t)pr * 512 + cc] = b;
                else          h1s0[(size_t)pr * 512 + (cc - 512)] = b;
            } else {
                gi_img[(size_t)pr * G3H + (cc - 1024)] = v + b_ih0[cc - 1024];
            }
        }
    }
}

// ---------------- gi GEMM: gi_all[t,p,:] = emb_bf16 @ w_ihe^T + gi_img ----------------
__global__ __launch_bounds__(256) void gemm_giemb(
    const unsigned short* __restrict__ embb,    // [VV][512]
    const unsigned short* __restrict__ wihe,    // [1536][512]
    const float* __restrict__ gi_img,           // [256][1536]
    const int* __restrict__ caps_ws, const int* __restrict__ len_ws,
    float* __restrict__ gi_all) {
    const int r0 = blockIdx.y * 64;
    const int t = r0 >> 8, p0 = r0 & 255;
    if (len_ws[p0] <= t) return;
    const int c0 = blockIdx.x * 64;
    const int tid = threadIdx.x;
    __shared__ unsigned short As[64][64 + FCP], Bs[64][64 + FCP];
    __shared__ int s_arow[64];
    if (tid < 64) s_arow[tid] = caps_ws[(p0 + tid) * TCAP + t];
    __syncthreads();
    const int lane = tid & 63, w = tid >> 6;
    f32x4 acc[4] = {};
    for (int k0 = 0; k0 < WDIM; k0 += 64) {
#pragma unroll
        for (int v = 0; v < 2; ++v) {
            int e = tid + v * 256;
            int rr = e >> 3, kk = (e & 7) * 8;
            *(short8v*)&As[rr][kk] = *(const short8v*)&embb[(size_t)s_arow[rr] * WDIM + k0 + kk];
            *(short8v*)&Bs[rr][kk] = *(const short8v*)&wihe[(size_t)(c0 + rr) * WDIM + k0 + kk];
        }
        __syncthreads();
#pragma unroll
        for (int ks = 0; ks < 64; ks += 32) {
            short8v a = *(const short8v*)&As[w * 16 + (lane & 15)][ks + (lane >> 4) * 8];
#pragma unroll
            for (int n = 0; n < 4; ++n) {
                short8v b = *(const short8v*)&Bs[n * 16 + (lane & 15)][ks + (lane >> 4) * 8];
                acc[n] = __builtin_amdgcn_mfma_f32_16x16x32_bf16(a, b, acc[n], 0, 0, 0);
            }
        }
        __syncthreads();
    }
#pragma unroll
    for (int n = 0; n < 4; ++n) {
        int cc = c0 + n * 16 + (lane & 15);
#pragma unroll
        for (int r = 0; r < 4; ++r) {
            int pr = p0 + w * 16 + (lane >> 4) * 4 + r;
            if (t < len_ws[pr])
                gi_all[((size_t)t * BB + pr) * G3H + cc] = acc[n][r] + gi_img[(size_t)pr * G3H + cc];
        }
    }
}

// ---------------- fused stage: blocks 0-95 gru, blocks 96-252 fc (one c0, both 128-row halves)
// 253 blocks total <= 256 CUs: every block runs on its own CU (no doubling on gru CUs).
__global__ __launch_bounds__(256, 1) void gru_fc_stage(int s,
    const unsigned short* __restrict__ h0_rd, unsigned short* __restrict__ h0_wr,
    float* __restrict__ gx_wr, const float* __restrict__ gx_rd,
    const unsigned short* __restrict__ h1_rd, unsigned short* __restrict__ h1_wr,
    unsigned short* __restrict__ h1x,
    const unsigned short* __restrict__ whh0b,   // [1536][512]
    const unsigned short* __restrict__ wih1b,   // [1536][512]
    const unsigned short* __restrict__ whh1b,   // [1536][512]
    const float* __restrict__ b_hh0, const float* __restrict__ gi_all,
    const float* __restrict__ b_ih1, const float* __restrict__ b_hh1,
    const unsigned short* __restrict__ fcwb,    // [VV][512]
    const float* __restrict__ fc_b,
    float* __restrict__ out,
    const int* __restrict__ len_ws) {
    __shared__ __align__(16) unsigned char smem_raw[55296];   // 54 KB, unioned
    const int bid = blockIdx.x;
    const int tid = threadIdx.x, lane = tid & 63, w = tid >> 6;

    if (bid < 96) {
        // ================= GRU part (validated) =================
        const int role = bid >> 5;
        const int sub = bid & 31;
        const int cc0 = (sub & 7) * 64;
        const int p0 = (sub >> 3) * 64;
        const int t = s - role;
        if (t < 0 || t >= TT) return;
        if (len_ws[p0] <= t) return;
        unsigned short (*Bs)[3][64][72] =
            reinterpret_cast<unsigned short (*)[3][64][72]>(smem_raw);
        const unsigned short* Arows = (role == 2) ? h1_rd : h0_rd;
        const unsigned short* Bw = (role == 0) ? whh0b : (role == 1) ? wih1b : whh1b;
        const int rr0 = tid >> 3, kk0 = (tid & 7) * 8;

        const int arow = p0 + w * 16 + (lane & 15);
        const int akoff = (lane >> 4) * 8;
        short8v af[16];
#pragma unroll
        for (int kc = 0; kc < 8; ++kc) {
            af[kc * 2]     = *(const short8v*)&Arows[(size_t)arow * 512 + kc * 64 + akoff];
            af[kc * 2 + 1] = *(const short8v*)&Arows[(size_t)arow * 512 + kc * 64 + 32 + akoff];
        }

        f32x4 aG0[4] = {}, aG1[4] = {}, aG2[4] = {};
        short8v pb[2][6];

#define LOADB(SL, KC) {                                                              \
    size_t ko = (size_t)(KC) * 64 + kk0;                                             \
    pb[SL][0] = *(const short8v*)&Bw[(size_t)(cc0 + rr0) * 512 + ko];                \
    pb[SL][1] = *(const short8v*)&Bw[(size_t)(cc0 + rr0 + 32) * 512 + ko];           \
    pb[SL][2] = *(const short8v*)&Bw[(size_t)(512 + cc0 + rr0) * 512 + ko];          \
    pb[SL][3] = *(const short8v*)&Bw[(size_t)(512 + cc0 + rr0 + 32) * 512 + ko];     \
    pb[SL][4] = *(const short8v*)&Bw[(size_t)(1024 + cc0 + rr0) * 512 + ko];         \
    pb[SL][5] = *(const short8v*)&Bw[(size_t)(1024 + cc0 + rr0 + 32) * 512 + ko]; }

        LOADB(0, 0);
        LOADB(1, 1);
#pragma unroll
        for (int kc = 0; kc < 8; ++kc) {
            const int sl = kc & 1;
            *(short8v*)&Bs[sl][0][rr0][kk0]      = pb[sl][0];
            *(short8v*)&Bs[sl][0][rr0 + 32][kk0] = pb[sl][1];
            *(short8v*)&Bs[sl][1][rr0][kk0]      = pb[sl][2];
            *(short8v*)&Bs[sl][1][rr0 + 32][kk0] = pb[sl][3];
            *(short8v*)&Bs[sl][2][rr0][kk0]      = pb[sl][4];
            *(short8v*)&Bs[sl][2][rr0 + 32][kk0] = pb[sl][5];
            __syncthreads();
            if (kc < 6) LOADB(sl, kc + 2);
#pragma unroll
            for (int ks = 0; ks < 2; ++ks) {
                short8v a = af[kc * 2 + ks];
#pragma unroll
                for (int n = 0; n < 4; ++n) {
                    int br = n * 16 + (lane & 15), bk = ks * 32 + (lane >> 4) * 8;
                    short8v b0 = *(const short8v*)&Bs[sl][0][br][bk];
                    aG0[n] = __builtin_amdgcn_mfma_f32_16x16x32_bf16(a, b0, aG0[n], 0, 0, 0);
                    short8v b1 = *(const short8v*)&Bs[sl][1][br][bk];
                    aG1[n] = __builtin_amdgcn_mfma_f32_16x16x32_bf16(a, b1, aG1[n], 0, 0, 0);
                    short8v b2 = *(const short8v*)&Bs[sl][2][br][bk];
                    aG2[n] = __builtin_amdgcn_mfma_f32_16x16x32_bf16(a, b2, aG2[n], 0, 0, 0);
                }
            }
        }
#undef LOADB

        if (role == 0) {
#pragma unroll
            for (int n = 0; n < 4; ++n) {
                int cc = cc0 + n * 16 + (lane & 15);
                float bR = b_hh0[cc], bZ = b_hh0[512 + cc], bN = b_hh0[1024 + cc];
#pragma unroll
                for (int r = 0; r < 4; ++r) {
                    int p = p0 + w * 16 + (lane >> 4) * 4 + r;
                    const float* gi = gi_all + ((size_t)t * BB + p) * G3H;
                    float rr_ = sigm(gi[cc] + aG0[n][r] + bR);
                    float zz  = sigm(gi[512 + cc] + aG1[n][r] + bZ);
                    float nn  = tanhf(gi[1024 + cc] + rr_ * (aG2[n][r] + bN));
                    float hold = bf2f(h0_rd[(size_t)p * 512 + cc]);
                    float hnew = (t < len_ws[p]) ? (1.f - zz) * nn + zz * hold : hold;
                    h0_wr[(size_t)p * 512 + cc] = f2bf(hnew);
                }
            }
        } else if (role == 1) {
#pragma unroll
            for (int n = 0; n < 4; ++n) {
                int cc = cc0 + n * 16 + (lane & 15);
                float bR = b_ih1[cc], bZ = b_ih1[512 + cc], bN = b_ih1[1024 + cc];
#pragma unroll
                for (int r = 0; r < 4; ++r) {
                    int p = p0 + w * 16 + (lane >> 4) * 4 + r;
                    float* gx = gx_wr + (size_t)p * G3H;
                    gx[cc]        = aG0[n][r] + bR;
                    gx[512 + cc]  = aG1[n][r] + bZ;
                    gx[1024 + cc] = aG2[n][r] + bN;
                }
            }
        } else {
#pragma unroll
            for (int n = 0; n < 4; ++n) {
                int cc = cc0 + n * 16 + (lane & 15);
                float bR = b_hh1[cc], bZ = b_hh1[512 + cc], bN = b_hh1[1024 + cc];
#pragma unroll
                for (int r = 0; r < 4; ++r) {
                    int p = p0 + w * 16 + (lane >> 4) * 4 + r;
                    const float* gx = gx_rd + (size_t)p * G3H;
                    float rr_ = sigm(gx[cc] + aG0[n][r] + bR);
                    float zz  = sigm(gx[512 + cc] + aG1[n][r] + bZ);
                    float nn  = tanhf(gx[1024 + cc] + rr_ * (aG2[n][r] + bN));
                    float hold = bf2f(h1_rd[(size_t)p * 512 + cc]);
                    float hnew = (t < len_ws[p]) ? (1.f - zz) * nn + zz * hold : hold;
                    unsigned short hb = f2bf(hnew);
                    h1_wr[(size_t)p * 512 + cc] = hb;
                    h1x[((size_t)t * BB + p) * 512 + cc] = hb;
                }
            }
        }
        return;
    }

    // ======= FC part: t = s-3; one c0 per block, loop over both 128-row halves =======
    const int t = s - 3;
    if (t < 0 || t >= TT) return;
    const int c0 = (bid - 96) * 64;              // 0..156 -> c0 0..9984
    unsigned short* smu = reinterpret_cast<unsigned short*>(smem_raw);
    const int rr0 = tid >> 3, kk0 = (tid & 7) * 8;

#pragma unroll
    for (int half = 0; half < 2; ++half) {
        const int p0 = half * 128;
        if (len_ws[p0] <= t) {                   // all 128 rows masked (sorted desc) -> zeros
            for (int e = tid; e < 128 * 16; e += 256) {
                int rl = e >> 4, c = c0 + (e & 15) * 4;
                if (c < VV) {
                    float4 z = {0.f, 0.f, 0.f, 0.f};
                    *(float4*)&out[((size_t)(p0 + rl) * TT + t) * VV + c] = z;
                }
            }
            continue;
        }
        f32x4 acc1[4] = {}, acc2[4] = {};
        short8v pf[2][6];

#define LOADF(SL, KC) {                                                                   \
    size_t ko = (size_t)(KC) * 64 + kk0;                                                  \
    pf[SL][0] = *(const short8v*)&h1x[((size_t)(t * BB + p0 + rr0)) * 512 + ko];          \
    pf[SL][1] = *(const short8v*)&h1x[((size_t)(t * BB + p0 + rr0 + 32)) * 512 + ko];     \
    pf[SL][2] = *(const short8v*)&h1x[((size_t)(t * BB + p0 + 64 + rr0)) * 512 + ko];     \
    pf[SL][3] = *(const short8v*)&h1x[((size_t)(t * BB + p0 + 64 + rr0 + 32)) * 512 + ko];\
    int bc1 = c0 + rr0, bc2 = c0 + rr0 + 32;                                              \
    short8v bv1 = {}, bv2 = {};                                                           \
    if (bc1 < VV) bv1 = *(const short8v*)&fcwb[(size_t)bc1 * 512 + ko];                   \
    if (bc2 < VV) bv2 = *(const short8v*)&fcwb[(size_t)bc2 * 512 + ko];                   \
    pf[SL][4] = bv1; pf[SL][5] = bv2; }

        LOADF(0, 0);
        LOADF(1, 1);
#pragma unroll
        for (int kc = 0; kc < 8; ++kc) {
            const int sl = kc & 1;
            unsigned short* tA1 = smu + (sl * 3 + 0) * 4608;   // 64*72
            unsigned short* tA2 = smu + (sl * 3 + 1) * 4608;
            unsigned short* tB  = smu + (sl * 3 + 2) * 4608;
            *(short8v*)&tA1[rr0 * 72 + kk0]        = pf[sl][0];
            *(short8v*)&tA1[(rr0 + 32) * 72 + kk0] = pf[sl][1];
            *(short8v*)&tA2[rr0 * 72 + kk0]        = pf[sl][2];
            *(short8v*)&tA2[(rr0 + 32) * 72 + kk0] = pf[sl][3];
            *(short8v*)&tB[rr0 * 72 + kk0]         = pf[sl][4];
            *(short8v*)&tB[(rr0 + 32) * 72 + kk0]  = pf[sl][5];
            __syncthreads();
            if (kc < 6) LOADF(sl, kc + 2);
#pragma unroll
            for (int ks = 0; ks < 2; ++ks) {
                int ar = w * 16 + (lane & 15), ak = ks * 32 + (lane >> 4) * 8;
                short8v a1 = *(const short8v*)&tA1[ar * 72 + ak];
                short8v a2 = *(const short8v*)&tA2[ar * 72 + ak];
#pragma unroll
                for (int n = 0; n < 4; ++n) {
                    short8v b = *(const short8v*)&tB[(n * 16 + (lane & 15)) * 72 + ak];
                    acc1[n] = __builtin_amdgcn_mfma_f32_16x16x32_bf16(a1, b, acc1[n], 0, 0, 0);
                    acc2[n] = __builtin_amdgcn_mfma_f32_16x16x32_bf16(a2, b, acc2[n], 0, 0, 0);
                }
            }
        }
#undef LOADF
#pragma unroll
        for (int n = 0; n < 4; ++n) {
            int c = c0 + n * 16 + (lane & 15);
            if (c < VV) {
                float bias = fc_b[c];
#pragma unroll
                for (int r = 0; r < 4; ++r) {
                    int pr1 = p0 + w * 16 + (lane >> 4) * 4 + r;
                    int pr2 = pr1 + 64;
                    bool a1 = (t < len_ws[pr1]);
                    bool a2 = (t < len_ws[pr2]);
                    out[((size_t)pr1 * TT + t) * VV + c] = a1 ? (acc1[n][r] + bias) : 0.f;
                    out[((size_t)pr2 * TT + t) * VV + c] = a2 ? (acc2[n][r] + bias) : 0.f;
                }
            }
        }
        // half transition is LDS-safe: every warp reaches next half's kc=0 barrier only
        // after fully completing this half; buffer parity alternates writes vs reads.
    }
}

// ---------------- launch ----------------
extern "C" void kernel_launch(void* const* d_in, const int* in_sizes, int n_in,
                              void* d_out, int out_size, void* d_ws, size_t ws_size,
                              hipStream_t stream) {
    const float* image_code = (const float*)d_in[0];
    const int*   captions   = (const int*)d_in[1];
    const int*   cap_lens   = (const int*)d_in[2];
    const float* embed_w    = (const float*)d_in[3];
    const float* init_w     = (const float*)d_in[4];
    const float* init_b     = (const float*)d_in[5];
    const float* w_ih0      = (const float*)d_in[6];
    const float* w_hh0      = (const float*)d_in[7];
    const float* b_ih0      = (const float*)d_in[8];
    const float* b_hh0      = (const float*)d_in[9];
    const float* w_ih1      = (const float*)d_in[10];
    const float* w_hh1      = (const float*)d_in[11];
    const float* b_ih1      = (const float*)d_in[12];
    const float* b_hh1      = (const float*)d_in[13];
    const float* fc_w       = (const float*)d_in[14];
    const float* fc_b       = (const float*)d_in[15];
    float* out = (float*)d_out;

    const size_t tail = (size_t)BB * TCAP + 2 * BB;     // 13,568
    const size_t predN = (size_t)out_size - tail;       // BB*TT*VV

    // ---- workspace ----
    char* ws = (char*)d_ws;
    int*   order_ws = (int*)(ws + 0);
    int*   len_ws   = (int*)(ws + 1024);
    int*   caps_ws  = (int*)(ws + 2048);
    unsigned short* h0s[2] = {(unsigned short*)(ws + 54272),  (unsigned short*)(ws + 316416)};
    unsigned short* h1s[2] = {(unsigned short*)(ws + 578560), (unsigned short*)(ws + 840704)};
    float* gxb[2] = {(float*)(ws + 1102848), (float*)(ws + 2675712)};
    float* gi_img   = (float*)(ws + 4248576);
    float* gi_all   = (float*)(ws + 5821440);
    unsigned short* h1x  = (unsigned short*)(ws + 84464640);
    unsigned short* fcwb = (unsigned short*)(ws + 97571840);
    unsigned short* whh0b_s = (unsigned short*)(ws + 110000128);
    unsigned short* wih1b_s = (unsigned short*)(ws + 111572992);
    unsigned short* whh1b_s = (unsigned short*)(ws + 113145856);

    // ---- bf16 staging in d_out's predictions region (consumed before fc writes) ----
    char* ob = (char*)d_out;
    unsigned short* imgb   = (unsigned short*)(ob + 0);          //  1,048,576 B
    unsigned short* wihe   = (unsigned short*)(ob + 1048576);    //  1,572,864 B
    unsigned short* wcomb  = (unsigned short*)(ob + 4194304);    // 10,485,760 B
    unsigned short* embb   = (unsigned short*)(ob + 16777216);   // 10,240,000 B

    dim3 blk(256);
    hipLaunchKernelGGL(sort_kernel, dim3(1), blk, 0, stream,
                       cap_lens, captions, order_ws, len_ws, caps_ws, out, predN);
    hipLaunchKernelGGL(gather_imgb, dim3(256), blk, 0, stream, image_code, order_ws, imgb);
    hipLaunchKernelGGL(cvt_mat, dim3(1024), blk, 0, stream,
                       init_w, ICC, 0, wcomb, ICC, 0, ICC, 1024 * ICC / 8);
    hipLaunchKernelGGL(cvt_mat, dim3(1536), blk, 0, stream,
                       w_ih0, ICC + WDIM, 0, wcomb + (size_t)1024 * ICC, ICC, 0, ICC, G3H * ICC / 8);
    hipLaunchKernelGGL(cvt_mat, dim3(384), blk, 0, stream,
                       w_ih0, ICC + WDIM, ICC, wihe, WDIM, 0, WDIM, G3H * WDIM / 8);
    hipLaunchKernelGGL(cvt_mat, dim3(2500), blk, 0, stream,
                       embed_w, WDIM, 0, embb, WDIM, 0, WDIM, VV * WDIM / 8);
    hipLaunchKernelGGL(cvt_mat, dim3(2500), blk, 0, stream,
                       fc_w, WDIM, 0, fcwb, WDIM, 0, WDIM, VV * WDIM / 8);
    hipLaunchKernelGGL(cvt_mat, dim3(384), blk, 0, stream,
                       w_hh0, WDIM, 0, whh0b_s, WDIM, 0, WDIM, G3H * WDIM / 8);
    hipLaunchKernelGGL(cvt_mat, dim3(384), blk, 0, stream,
                       w_ih1, WDIM, 0, wih1b_s, WDIM, 0, WDIM, G3H * WDIM / 8);
    hipLaunchKernelGGL(cvt_mat, dim3(384), blk, 0, stream,
                       w_hh1, WDIM, 0, whh1b_s, WDIM, 0, WDIM, G3H * WDIM / 8);

    hipLaunchKernelGGL(gemm_front, dim3(40, 4), blk, 0, stream,
                       imgb, wcomb, init_b, b_ih0, h0s[0], h1s[0], gi_img);
    hipLaunchKernelGGL(gemm_giemb, dim3(24, 200), blk, 0, stream,
                       embb, wihe, gi_img, caps_ws, len_ws, gi_all);

    // 53 fused stages: stage s = { l0@s, gx1@s-1, l1h@s-2, fc@s-3 }
    for (int s = 0; s <= TT + 2; ++s) {
        int q = s & 1;
        hipLaunchKernelGGL(gru_fc_stage, dim3(96 + 157), blk, 0, stream, s,
                           h0s[q], h0s[q ^ 1],
                           gxb[q ^ 1], gxb[q],
                           h1s[q], h1s[q ^ 1],
                           h1x, whh0b_s, wih1b_s, whh1b_s,
                           b_hh0, gi_all, b_ih1, b_hh1,
                           fcwb, fc_b, out, len_ws);
    }
}